// Round 4
// baseline (1270.229 us; speedup 1.0000x reference)
//
#include <hip/hip_runtime.h>
#include <math.h>

static constexpr int Zc  = 64;
static constexpr int Xc  = 32;
static constexpr int THc = 128;
static constexpr int OHc = 64;
static constexpr int Bc  = 4096;
static constexpr int Tc  = 256;

__device__ __forceinline__ float sigf(float x) {
  float e = __expf(-x);
  return __builtin_amdgcn_rcpf(1.0f + e);
}
__device__ __forceinline__ float tanh_fast(float x) {
  float xc = fminf(fmaxf(x, -15.0f), 15.0f);
  float e  = __expf(-2.0f * xc);
  return (1.0f - e) * __builtin_amdgcn_rcpf(1.0f + e);
}
__device__ __forceinline__ float dot4(float4 w, float4 v) {
  return fmaf(w.x, v.x, fmaf(w.y, v.y, fmaf(w.z, v.z, w.w * v.w)));
}

// All weight storage is NAMED float4 locals (w0..w19) — no arrays, so the
// compiler cannot demote them to scratch. Indexing is 100% compile-time.
#define LD16(A,B,C,D, SP) do { const float4* _p = (const float4*)(SP); \
    A = _p[0]; B = _p[1]; C = _p[2]; D = _p[3]; } while (0)
#define LD32(A,B,C,D,E,F,G,H, SP) do { LD16(A,B,C,D, SP); \
    LD16(E,F,G,H, ((const float*)(SP)) + 16); } while (0)

#define DOT16(A,B,C,D, XP) \
  (dot4(A, ((const float4*)(XP))[0]) + dot4(B, ((const float4*)(XP))[1]) + \
   dot4(C, ((const float4*)(XP))[2]) + dot4(D, ((const float4*)(XP))[3]))
#define DOT32(A,B,C,D,E,F,G,H, XP) \
  (DOT16(A,B,C,D, XP) + DOT16(E,F,G,H, ((const float*)(XP)) + 16))
#define DOT64(A,B,C,D,E,F,G,H,I,J,K,L,M,N,O,P, XP) \
  (DOT32(A,B,C,D,E,F,G,H, XP) + DOT32(I,J,K,L,M,N,O,P, ((const float*)(XP)) + 32))

// Serial recurrence, 1 block x 1024 threads (16 waves), 3 barriers/step.
// Wave roles:
//   0-7  : P1 GRU (8 lanes per output j, xor8/16/32 reduce)  [48 floats]
//          P2 trans half-rows gzh (w0-3) / pzh (w4-7)         [+32 floats]
//   8-9  : P1 obs hidden (olh / osh, full rows)               [64 floats]
//   10   : P2 z_lin (W_zloc full rows)                        [64 floats]
//   11   : P2 obs final (olx lanes 0-31 / osx lanes 32-63)    [64 floats]
//   12-15: P3 gate+pm quarter-rows (xor16/32 reduce)          [64 floats]
__global__ __launch_bounds__(1024, 4) void chain_kernel(
    const float* __restrict__ z0, const float* __restrict__ h0,
    const float* __restrict__ W_ih, const float* __restrict__ W_hh,
    const float* __restrict__ b_ih, const float* __restrict__ b_hh,
    const float* __restrict__ W_gzh, const float* __restrict__ b_gzh,
    const float* __restrict__ W_ghz, const float* __restrict__ b_ghz,
    const float* __restrict__ W_pzh, const float* __restrict__ b_pzh,
    const float* __restrict__ W_phz, const float* __restrict__ b_phz,
    const float* __restrict__ W_zloc, const float* __restrict__ b_zloc,
    const float* __restrict__ W_olh, const float* __restrict__ b_olh,
    const float* __restrict__ W_olx, const float* __restrict__ b_olx,
    const float* __restrict__ W_osh, const float* __restrict__ b_osh,
    const float* __restrict__ W_osx, const float* __restrict__ b_osx,
    float* __restrict__ out) {
  const int tid  = threadIdx.x;
  const int lane = tid & 63;
  const int wv   = tid >> 6;   // 0..15

  __shared__ __align__(16) float zbuf[64];
  __shared__ __align__(16) float hA[64];
  __shared__ __align__(16) float hB[64];
  __shared__ __align__(16) float abuf[128];
  __shared__ __align__(16) float cbuf[128];
  __shared__ __align__(16) float zlinbuf[64];
  __shared__ __align__(16) float olbuf[64];
  __shared__ __align__(16) float osbuf[64];

  float4 w0{},w1{},w2{},w3{},w4{},w5{},w6{},w7{},w8{},w9{},
         w10{},w11{},w12{},w13{},w14{},w15{},w16{},w17{},w18{},w19{};
  float bA = 0.f, bB = 0.f, bC = 0.f, bD = 0.f, b2 = 0.f;

  // ---------------- weight staging ----------------
  if (wv < 8) {
    // GRU: output j, 16-col chunk q of concat [z|h] (q<4: W_ih, q>=4: W_hh)
    const int j = (wv << 3) + (lane & 7);
    const int q = lane >> 3;
    const float* Ws = (q < 4) ? W_ih : W_hh;
    const int c = (q & 3) * 16;
    LD16(w0, w1, w2, w3,  Ws + (j) * 64 + c);        // r row chunk
    LD16(w4, w5, w6, w7,  Ws + (64 + j) * 64 + c);   // u row chunk
    LD16(w8, w9, w10, w11, Ws + (128 + j) * 64 + c); // n row chunk
    bA = b_ih[j] + b_hh[j];
    bB = b_ih[64 + j] + b_hh[64 + j];
    bC = b_ih[128 + j];
    bD = b_hh[128 + j];
    // P2 half-row
    const int row  = ((wv & 3) << 5) + (lane & 31);
    const int half = lane >> 5;
    const float* Wp = (wv < 4) ? W_gzh : W_pzh;
    LD32(w12, w13, w14, w15, w16, w17, w18, w19, Wp + row * 64 + half * 32);
    b2 = (wv < 4) ? b_gzh[row] : b_pzh[row];
  } else if (wv < 10) {
    const float* Ws = (wv == 8) ? W_olh : W_osh;
    LD32(w0, w1, w2, w3, w4, w5, w6, w7,        Ws + lane * 64);
    LD32(w8, w9, w10, w11, w12, w13, w14, w15,  Ws + lane * 64 + 32);
    b2 = (wv == 8) ? b_olh[lane] : b_osh[lane];
  } else if (wv == 10) {
    LD32(w0, w1, w2, w3, w4, w5, w6, w7,        W_zloc + lane * 64);
    LD32(w8, w9, w10, w11, w12, w13, w14, w15,  W_zloc + lane * 64 + 32);
    b2 = b_zloc[lane];
  } else if (wv == 11) {
    const int r = lane & 31;
    const float* Ws = (lane < 32) ? W_olx : W_osx;
    LD32(w0, w1, w2, w3, w4, w5, w6, w7,        Ws + r * 64);
    LD32(w8, w9, w10, w11, w12, w13, w14, w15,  Ws + r * 64 + 32);
    b2 = (lane < 32) ? b_olx[r] : b_osx[r];
  } else {
    // P3: j-output, 32-col quarter q of TH=128
    const int j = ((wv & 3) << 4) + (lane & 15);
    const int q = lane >> 4;
    LD32(w0, w1, w2, w3, w4, w5, w6, w7,        W_ghz + j * 128 + q * 32);
    LD32(w8, w9, w10, w11, w12, w13, w14, w15,  W_phz + j * 128 + q * 32);
    bA = b_ghz[j];
    bB = b_phz[j];
  }

  if (tid < 64) { zbuf[tid] = z0[tid]; hA[tid] = h0[tid]; }
  __syncthreads();

  for (int t = 0; t <= Tc; ++t) {
    const bool step = (t < Tc);
    const bool obs  = (t >= 1);
    float* hold = (t & 1) ? hB : hA;
    float* hnew = (t & 1) ? hA : hB;

    // ---- P1: GRU (waves 0-7) || obs hidden of step t-1 (waves 8-9) ----
    if (step && wv < 8) {
      const int j = (wv << 3) + (lane & 7);
      const int q = lane >> 3;
      const float* x = ((q < 4) ? zbuf : hold) + (q & 3) * 16;
      float pr = DOT16(w0, w1, w2, w3, x);
      float pu = DOT16(w4, w5, w6, w7, x);
      float pn = DOT16(w8, w9, w10, w11, x);
      pr += __shfl_xor(pr, 8, 64);  pr += __shfl_xor(pr, 16, 64); pr += __shfl_xor(pr, 32, 64);
      pu += __shfl_xor(pu, 8, 64);  pu += __shfl_xor(pu, 16, 64); pu += __shfl_xor(pu, 32, 64);
      pn += __shfl_xor(pn, 8, 64);  pn += __shfl_xor(pn, 16, 64);
      float pno = __shfl_xor(pn, 32, 64);
      float i_n = ((q < 4) ? pn : pno) + bC;
      float h_n = ((q < 4) ? pno : pn) + bD;
      float r  = sigf(pr + bA);
      float u  = sigf(pu + bB);
      float nn = tanh_fast(i_n + r * h_n);
      float hv = (1.f - u) * nn + u * hold[j];
      if (q == 0) hnew[j] = hv;
    }
    if (obs && (wv == 8 || wv == 9)) {
      float acc = DOT64(w0, w1, w2, w3, w4, w5, w6, w7,
                        w8, w9, w10, w11, w12, w13, w14, w15, zbuf) + b2;
      acc = fmaxf(acc, 0.f);
      if (wv == 8) olbuf[lane] = acc; else osbuf[lane] = acc;
    }
    __syncthreads();

    // ---- P2: trans hiddens (waves 0-7) + z_lin (10) || obs final (11) ----
    if (step && wv < 8) {
      const int row  = ((wv & 3) << 5) + (lane & 31);
      const int half = lane >> 5;
      float s = DOT32(w12, w13, w14, w15, w16, w17, w18, w19, hnew + half * 32);
      s += __shfl_xor(s, 32, 64);
      if (lane < 32) {
        float v = fmaxf(s + b2, 0.f);
        if (wv < 4) abuf[row] = v; else cbuf[row] = v;
      }
    }
    if (step && wv == 10) {
      zlinbuf[lane] = DOT64(w0, w1, w2, w3, w4, w5, w6, w7,
                            w8, w9, w10, w11, w12, w13, w14, w15, hnew) + b2;
    }
    if (obs && wv == 11) {
      const float* x = (lane < 32) ? olbuf : osbuf;
      float acc = DOT64(w0, w1, w2, w3, w4, w5, w6, w7,
                        w8, w9, w10, w11, w12, w13, w14, w15, x) + b2;
      out[(size_t)(t - 1) * 64 + lane] = fmaxf(acc, 0.f);
    }
    __syncthreads();

    // ---- P3: gate + pm + z combine (waves 12-15) ----
    if (step && wv >= 12) {
      const int j = ((wv & 3) << 4) + (lane & 15);
      const int q = lane >> 4;
      float sg = DOT32(w0, w1, w2, w3, w4, w5, w6, w7, abuf + q * 32);
      float sp = DOT32(w8, w9, w10, w11, w12, w13, w14, w15, cbuf + q * 32);
      sg += __shfl_xor(sg, 16, 64); sg += __shfl_xor(sg, 32, 64);
      sp += __shfl_xor(sp, 16, 64); sp += __shfl_xor(sp, 32, 64);
      if (q == 0) {
        float g = sigf(sg + bA);
        zbuf[j] = (1.f - g) * zlinbuf[j] + g * (sp + bB);
      }
    }
    __syncthreads();
  }
}

// out[n] = out[n mod 16384] for n >= 16384; 16384 = T*2X is a power of two.
__global__ __launch_bounds__(256) void bcast_kernel(float* __restrict__ out) {
  const size_t total4 = (size_t)Bc * Tc * (2 * Xc) / 4;
  const size_t src4   = (size_t)Tc * (2 * Xc) / 4;
  const float4* s = (const float4*)out;
  float4* o = (float4*)out;
  size_t stride = (size_t)gridDim.x * blockDim.x;
  for (size_t i = (size_t)blockIdx.x * blockDim.x + threadIdx.x + src4;
       i < total4; i += stride) {
    o[i] = s[i & (src4 - 1)];
  }
}

extern "C" void kernel_launch(void* const* d_in, const int* in_sizes, int n_in,
                              void* d_out, int out_size, void* d_ws, size_t ws_size,
                              hipStream_t stream) {
  (void)in_sizes; (void)n_in; (void)d_ws; (void)ws_size; (void)out_size;
  const float* z0     = (const float*)d_in[1];
  const float* h0     = (const float*)d_in[2];
  const float* W_ih   = (const float*)d_in[3];
  const float* W_hh   = (const float*)d_in[4];
  const float* b_ih   = (const float*)d_in[5];
  const float* b_hh   = (const float*)d_in[6];
  const float* W_gzh  = (const float*)d_in[7];
  const float* b_gzh  = (const float*)d_in[8];
  const float* W_ghz  = (const float*)d_in[9];
  const float* b_ghz  = (const float*)d_in[10];
  const float* W_pzh  = (const float*)d_in[11];
  const float* b_pzh  = (const float*)d_in[12];
  const float* W_phz  = (const float*)d_in[13];
  const float* b_phz  = (const float*)d_in[14];
  const float* W_zloc = (const float*)d_in[15];
  const float* b_zloc = (const float*)d_in[16];
  const float* W_olh  = (const float*)d_in[19];
  const float* b_olh  = (const float*)d_in[20];
  const float* W_olx  = (const float*)d_in[21];
  const float* b_olx  = (const float*)d_in[22];
  const float* W_osh  = (const float*)d_in[23];
  const float* b_osh  = (const float*)d_in[24];
  const float* W_osx  = (const float*)d_in[25];
  const float* b_osx  = (const float*)d_in[26];
  float* out = (float*)d_out;

  chain_kernel<<<1, 1024, 0, stream>>>(
      z0, h0, W_ih, W_hh, b_ih, b_hh,
      W_gzh, b_gzh, W_ghz, b_ghz, W_pzh, b_pzh, W_phz, b_phz,
      W_zloc, b_zloc, W_olh, b_olh, W_olx, b_olx,
      W_osh, b_osh, W_osx, b_osx, out);

  bcast_kernel<<<2048, 256, 0, stream>>>(out);
}

// Round 5
// 627.094 us; speedup vs baseline: 2.0256x; 2.0256x over previous
//
#include <hip/hip_runtime.h>
#include <math.h>

// Problem constants (from reference)
static constexpr int Zc  = 64;    // z_dim
static constexpr int Xc  = 32;    // x_dim
static constexpr int THc = 128;   // trans_hidden
static constexpr int OHc = 64;    // obs_hidden
static constexpr int Bc  = 4096;  // batch
static constexpr int Tc  = 256;   // time

__device__ __forceinline__ float sigf(float x) {
  float e = __expf(-x);
  return __builtin_amdgcn_rcpf(1.0f + e);
}
__device__ __forceinline__ float tanh_fast(float x) {
  float xc = fminf(fmaxf(x, -15.0f), 15.0f);
  float e  = __expf(-2.0f * xc);
  return (1.0f - e) * __builtin_amdgcn_rcpf(1.0f + e);
}

// dot of 32 register weights (constant offset into wbig) with 32 LDS floats
template <int OFF>
__device__ __forceinline__ float dot32(const float (&w)[160], const float* x) {
  float a0 = 0.f, a1 = 0.f, a2 = 0.f, a3 = 0.f;
#pragma unroll
  for (int k = 0; k < 8; ++k) {
    float4 v = ((const float4*)x)[k];
    a0 = fmaf(w[OFF + 4 * k + 0], v.x, a0);
    a1 = fmaf(w[OFF + 4 * k + 1], v.y, a1);
    a2 = fmaf(w[OFF + 4 * k + 2], v.z, a2);
    a3 = fmaf(w[OFF + 4 * k + 3], v.w, a3);
  }
  return (a0 + a1) + (a2 + a3);
}

template <int OFF>
__device__ __forceinline__ float dot64(const float (&w)[160], const float* x) {
  float a0 = 0.f, a1 = 0.f, a2 = 0.f, a3 = 0.f;
#pragma unroll
  for (int k = 0; k < 16; ++k) {
    float4 v = ((const float4*)x)[k];
    a0 = fmaf(w[OFF + 4 * k + 0], v.x, a0);
    a1 = fmaf(w[OFF + 4 * k + 1], v.y, a1);
    a2 = fmaf(w[OFF + 4 * k + 2], v.z, a2);
    a3 = fmaf(w[OFF + 4 * k + 3], v.w, a3);
  }
  return (a0 + a1) + (a2 + a3);
}

template <int OFF>
__device__ __forceinline__ void load32(float (&w)[160], const float* src) {
#pragma unroll
  for (int k = 0; k < 8; ++k) {
    float4 v = ((const float4*)src)[k];
    w[OFF + 4 * k + 0] = v.x; w[OFF + 4 * k + 1] = v.y;
    w[OFF + 4 * k + 2] = v.z; w[OFF + 4 * k + 3] = v.w;
  }
}
template <int OFF>
__device__ __forceinline__ void load64(float (&w)[160], const float* src) {
  load32<OFF>(w, src);
  load32<OFF + 32>(w, src + 32);
}

// Serial recurrence, 1 block x 512 threads (8 waves), 3 barriers per step.
//   P1: rnn_out (fused GRU matvec+elementwise, waves 0-3, shfl-reduced)
//       || obs hidden for step t-1 (waves 4-5)
//   P2: trans hiddens + z_lin (waves 0-4) || obs final -> out[t-1] (wave 5)
//   P3: gate+pm+z combine in-lane (waves 6-7)
// Weights live in per-thread registers (wbig[160] overlay, template offsets).
// __launch_bounds__(512, 1): second arg behaves like CUDA minBlocksPerCU
// (R2/R3 evidence: (512,2)->128 VGPR, (1024,4)->64 VGPR). 1 block/CU ->
// 2 waves/SIMD -> 256-VGPR budget, so wbig[160] can live in registers.
__global__ __launch_bounds__(512, 1) void chain_kernel(
    const float* __restrict__ z0, const float* __restrict__ h0,
    const float* __restrict__ W_ih, const float* __restrict__ W_hh,
    const float* __restrict__ b_ih, const float* __restrict__ b_hh,
    const float* __restrict__ W_gzh, const float* __restrict__ b_gzh,
    const float* __restrict__ W_ghz, const float* __restrict__ b_ghz,
    const float* __restrict__ W_pzh, const float* __restrict__ b_pzh,
    const float* __restrict__ W_phz, const float* __restrict__ b_phz,
    const float* __restrict__ W_zloc, const float* __restrict__ b_zloc,
    const float* __restrict__ W_olh, const float* __restrict__ b_olh,
    const float* __restrict__ W_olx, const float* __restrict__ b_olx,
    const float* __restrict__ W_osh, const float* __restrict__ b_osh,
    const float* __restrict__ W_osx, const float* __restrict__ b_osx,
    float* __restrict__ out) {
  const int tid  = threadIdx.x;
  const int lane = tid & 63;
  const int wv   = tid >> 6;

  __shared__ __align__(16) float zbuf[64];
  __shared__ __align__(16) float hA[64];
  __shared__ __align__(16) float hB[64];
  __shared__ __align__(16) float abuf[128];
  __shared__ __align__(16) float cbuf[128];
  __shared__ __align__(16) float zlinbuf[64];
  __shared__ __align__(16) float olbuf[64];
  __shared__ __align__(16) float osbuf[64];

  float wbig[160];
  float bA = 0.f, bB = 0.f, bC = 0.f, bD = 0.f, b2 = 0.f;

  // ---------------- weight staging into registers ----------------
  if (tid < 256) {
    // waves 0-3: GRU. j = output index, q = quarter-chunk of concat [z|h].
    const int j = (wv << 4) + (lane & 15);
    const int q = lane >> 4;
    const float* Wz = (q < 2) ? W_ih : W_hh;
    const int coff = (q & 1) * 32;
    load32<0 >(wbig, Wz + (j) * 64 + coff);        // r row chunk
    load32<32>(wbig, Wz + (64 + j) * 64 + coff);   // u row chunk
    load32<64>(wbig, Wz + (128 + j) * 64 + coff);  // n row chunk (i_n / h_n part)
    bA = b_ih[j] + b_hh[j];
    bB = b_ih[64 + j] + b_hh[64 + j];
    bC = b_ih[128 + j];
    bD = b_hh[128 + j];
    if (tid < 128) { load64<96>(wbig, W_gzh + tid * 64);         b2 = b_gzh[tid]; }
    else           { load64<96>(wbig, W_pzh + (tid - 128) * 64); b2 = b_pzh[tid - 128]; }
  } else if (tid < 320) {
    // wave 4: obs-loc hidden row + zloc row
    const int r = tid - 256;
    load64<0 >(wbig, W_olh + r * 64);  bA = b_olh[r];
    load64<96>(wbig, W_zloc + r * 64); b2 = b_zloc[r];
  } else if (tid < 384) {
    // wave 5: obs-scale hidden row + obs final row
    const int r = tid - 320;
    load64<0>(wbig, W_osh + r * 64);   bA = b_osh[r];
    if (tid < 352) { load64<96>(wbig, W_olx + r * 64);          b2 = b_olx[r]; }
    else           { load64<96>(wbig, W_osx + (tid - 352) * 64); b2 = b_osx[tid - 352]; }
  } else {
    // waves 6-7: gate + pm half-rows. j = row, half = K-half of TH=128.
    const int j    = ((wv & 1) << 5) + (lane & 31);
    const int half = lane >> 5;
    load64<0 >(wbig, W_ghz + j * 128 + half * 64); bA = b_ghz[j];
    load64<64>(wbig, W_phz + j * 128 + half * 64); bB = b_phz[j];
  }

  if (tid < 64) { zbuf[tid] = z0[tid]; hA[tid] = h0[tid]; }
  __syncthreads();

  for (int t = 0; t <= Tc; ++t) {
    const bool step = (t < Tc);
    const bool obs  = (t >= 1);
    float* hold = (t & 1) ? hB : hA;
    float* hnew = (t & 1) ? hA : hB;

    // ---- P1: rnn_out (fused GRU) || obs hidden (t-1) ----
    if (step && tid < 256) {
      const int j = (wv << 4) + (lane & 15);
      const int q = lane >> 4;
      const float* x = ((q < 2) ? zbuf : hold) + (q & 1) * 32;
      float pr = dot32<0 >(wbig, x);
      float pu = dot32<32>(wbig, x);
      float pn = dot32<64>(wbig, x);
      pr += __shfl_xor(pr, 16, 64); pr += __shfl_xor(pr, 32, 64);
      pu += __shfl_xor(pu, 16, 64); pu += __shfl_xor(pu, 32, 64);
      pn += __shfl_xor(pn, 16, 64);
      float pno = __shfl_xor(pn, 32, 64);
      float i_n = ((lane < 32) ? pn : pno) + bC;
      float h_n = ((lane < 32) ? pno : pn) + bD;
      float r  = sigf(pr + bA);
      float u  = sigf(pu + bB);
      float nn = tanh_fast(i_n + r * h_n);
      float hv = (1.f - u) * nn + u * hold[j];
      if (lane < 16) hnew[j] = hv;
    }
    if (obs && tid >= 256 && tid < 384) {
      const int r = (tid < 320) ? (tid - 256) : (tid - 320);
      float acc = dot64<0>(wbig, zbuf) + bA;   // zbuf holds Z_t (for out[t-1])
      acc = fmaxf(acc, 0.f);
      if (tid < 320) olbuf[r] = acc; else osbuf[r] = acc;
    }
    __syncthreads();

    // ---- P2: trans hiddens + z_lin || obs final -> out[t-1] ----
    if (step && tid < 320) {
      float acc = dot64<96>(wbig, hnew) + b2;
      if (tid < 128)      abuf[tid] = fmaxf(acc, 0.f);
      else if (tid < 256) cbuf[tid - 128] = fmaxf(acc, 0.f);
      else                zlinbuf[tid - 256] = acc;
    }
    if (obs && tid >= 320 && tid < 384) {
      const float* x = (tid < 352) ? olbuf : osbuf;
      float acc = dot64<96>(wbig, x) + b2;
      out[(size_t)(t - 1) * 64 + (tid - 320)] = fmaxf(acc, 0.f);
    }
    __syncthreads();

    // ---- P3: gate + pm + z combine (waves 6-7, in-lane) ----
    if (step && tid >= 384) {
      const int j    = ((wv & 1) << 5) + (lane & 31);
      const int half = lane >> 5;
      float sg = dot64<0 >(wbig, abuf + half * 64);
      float sp = dot64<64>(wbig, cbuf + half * 64);
      sg += __shfl_xor(sg, 32, 64);
      sp += __shfl_xor(sp, 32, 64);
      float zl = zlinbuf[j];
      float g  = sigf(sg + bA);
      float zv = (1.f - g) * zl + g * (sp + bB);
      if (lane < 32) zbuf[j] = zv;
    }
    __syncthreads();
  }
}

// out[n] = out[n mod 16384] for n >= 16384; 16384 = T*2X is a power of two.
__global__ __launch_bounds__(256) void bcast_kernel(float* __restrict__ out) {
  const size_t total4 = (size_t)Bc * Tc * (2 * Xc) / 4;  // 16,777,216 float4
  const size_t src4   = (size_t)Tc * (2 * Xc) / 4;        // 4096 float4
  const float4* s = (const float4*)out;
  float4* o = (float4*)out;
  size_t stride = (size_t)gridDim.x * blockDim.x;
  for (size_t i = (size_t)blockIdx.x * blockDim.x + threadIdx.x + src4;
       i < total4; i += stride) {
    o[i] = s[i & (src4 - 1)];
  }
}

extern "C" void kernel_launch(void* const* d_in, const int* in_sizes, int n_in,
                              void* d_out, int out_size, void* d_ws, size_t ws_size,
                              hipStream_t stream) {
  (void)in_sizes; (void)n_in; (void)d_ws; (void)ws_size; (void)out_size;
  const float* z0     = (const float*)d_in[1];
  const float* h0     = (const float*)d_in[2];
  const float* W_ih   = (const float*)d_in[3];
  const float* W_hh   = (const float*)d_in[4];
  const float* b_ih   = (const float*)d_in[5];
  const float* b_hh   = (const float*)d_in[6];
  const float* W_gzh  = (const float*)d_in[7];
  const float* b_gzh  = (const float*)d_in[8];
  const float* W_ghz  = (const float*)d_in[9];
  const float* b_ghz  = (const float*)d_in[10];
  const float* W_pzh  = (const float*)d_in[11];
  const float* b_pzh  = (const float*)d_in[12];
  const float* W_phz  = (const float*)d_in[13];
  const float* b_phz  = (const float*)d_in[14];
  const float* W_zloc = (const float*)d_in[15];
  const float* b_zloc = (const float*)d_in[16];
  const float* W_olh  = (const float*)d_in[19];
  const float* b_olh  = (const float*)d_in[20];
  const float* W_olx  = (const float*)d_in[21];
  const float* b_olx  = (const float*)d_in[22];
  const float* W_osh  = (const float*)d_in[23];
  const float* b_osh  = (const float*)d_in[24];
  const float* W_osx  = (const float*)d_in[25];
  const float* b_osx  = (const float*)d_in[26];
  float* out = (float*)d_out;

  chain_kernel<<<1, 512, 0, stream>>>(
      z0, h0, W_ih, W_hh, b_ih, b_hh,
      W_gzh, b_gzh, W_ghz, b_ghz, W_pzh, b_pzh, W_phz, b_phz,
      W_zloc, b_zloc, W_olh, b_olh, W_olx, b_olx,
      W_osh, b_osh, W_osx, b_osx, out);

  bcast_kernel<<<2048, 256, 0, stream>>>(out);
}